// Round 7
// baseline (187.107 us; speedup 1.0000x reference)
//
#include <hip/hip_runtime.h>

#define N_PTS 50000
#define M 32
#define KP 15
#define D 64
#define E1 45
#define P 16       // points per block (512 threads, 8 waves)
#define WFS 1048   // wfh plane row stride (ushorts): >=1024 enum slots
#define AWR 36     // aw row stride (ushorts): 18 dwords -> conflict-free b128 frags
#define AWP 576    // aw plane size (16 rows * 36)
#define AWB 1152   // per-point region stride in bufB (hi plane + lo plane)

typedef __attribute__((ext_vector_type(8))) _Float16 f16x8;
typedef __attribute__((ext_vector_type(4))) float    f32x4;
typedef __attribute__((ext_vector_type(2))) _Float16 f16x2;
typedef __attribute__((ext_vector_type(2))) __fp16   fp16v2;   // builtin return type

__device__ __forceinline__ unsigned pkrtz(float a, float b) {   // packed fp16 RTZ
    union { fp16v2 v; unsigned u; } x;
    x.v = __builtin_amdgcn_cvt_pkrtz(a, b);
    return x.u;
}
__device__ __forceinline__ unsigned pkrne(float a, float b) {   // packed fp16 RNE
    union { f16x2 v; unsigned u; } x;
    x.v[0] = (_Float16)a; x.v[1] = (_Float16)b; return x.u;
}
__device__ __forceinline__ float h2f(unsigned bits16) {
    union { unsigned short s; _Float16 h; } x; x.s = (unsigned short)bits16;
    return (float)x.h;
}
// compensated fp16 split of a pair: hu = packed hi (RTZ), lu = packed residual
__device__ __forceinline__ void split2h(float a, float b, unsigned& hu, unsigned& lu) {
    hu = pkrtz(a, b);
    const float ra = a - h2f(hu & 0xffffu);
    const float rb = b - h2f(hu >> 16);
    lu = pkrtz(ra, rb);
}
// packed single value split: lo16 = fp16 hi (RNE), hi16 = fp16 residual
__device__ __forceinline__ unsigned splitpk1(float v) {
    const _Float16 h = (_Float16)v;
    const _Float16 l = (_Float16)(v - (float)h);
    union { f16x2 v2; unsigned u; } x; x.v2[0] = h; x.v2[1] = l; return x.u;
}
__device__ __forceinline__ unsigned u4c(const uint4 v, const int t) {
    return (t == 0) ? v.x : (t == 1) ? v.y : (t == 2) ? v.z : v.w;
}

#if defined(__HIP_DEVICE_COMPILE__) && __has_builtin(__builtin_amdgcn_perm)
__device__ __forceinline__ unsigned permb(unsigned a, unsigned b, unsigned sel) {
    return __builtin_amdgcn_perm(a, b, sel);
}
#else
__device__ __forceinline__ unsigned permb(unsigned a, unsigned b, unsigned sel) {
    if (sel == 0x05040100u) return (b & 0xffffu) | (a << 16);
    return (b >> 16) | (a & 0xffff0000u);
}
#endif

// ---------------- fused prep (one launch; writes d_ws) -----------------------
// blocks [0,3125): x -> packed {f16 hi, f16 residual} dwords, TRANSPOSED row
//     layout: xw[n*64 + c*4 + t] holds x[n][t*16+c]  (c=0..15, t=0..3)
// blocks [3125,3317): ow -> owh/owl fp16 planes; pos swizzle:
//     orig = pos ^ (((pos>>6)&3)<<2); d = orig>>4, k = orig&15 (zero pad k==15/e>=45)
// blocks [3317,3557): w -> wh single fp16 plane; pos = k*64+dsw, d = dsw ^ ((k&7)<<3)
__global__ void prep_all(const float* __restrict__ x, const float* __restrict__ ow,
                         const float* __restrict__ w, unsigned* __restrict__ xw,
                         unsigned short* __restrict__ owh, unsigned short* __restrict__ owl,
                         unsigned short* __restrict__ wh)
{
    const int b = blockIdx.x, tid = threadIdx.x;
    if (b < 3125) {
        const int i = b * 256 + tid;                 // float4 index
        const float4 v = ((const float4*)x)[i];
        const int e0 = i * 4;
        const int n = e0 >> 6, d0 = e0 & 63;
        const int t = d0 >> 4, c0 = d0 & 15;         // 4 consecutive c, same t
        unsigned* dst = xw + n * 64 + t;
        dst[(c0 + 0) * 4] = splitpk1(v.x);
        dst[(c0 + 1) * 4] = splitpk1(v.y);
        dst[(c0 + 2) * 4] = splitpk1(v.z);
        dst[(c0 + 3) * 4] = splitpk1(v.w);
    } else if (b < 3317) {
        const int t = (b - 3125) * 256 + tid;               // [0, 49152)
        const int j = t & 7, lane = (t >> 3) & 63, rest = t >> 9;
        const int nt = rest % 3, ks = rest / 3;
        const int q = lane >> 4, c = lane & 15;
        const int pos  = ks * 32 + q * 8 + j;
        const int orig = pos ^ (((pos >> 6) & 3) << 2);
        const int d = orig >> 4, k = orig & 15, e = nt * 16 + c;
        const float v = (k < KP && e < E1) ? ow[k * (D * E1) + d * E1 + e] : 0.f;
        const unsigned u = splitpk1(v);
        owh[t] = (unsigned short)u;
        owl[t] = (unsigned short)(u >> 16);
    } else {
        const int t = (b - 3317) * 256 + tid;               // [0, 61440)
        const int j = t & 7, lane = (t >> 3) & 63, rest = t >> 9;
        const int nt = rest & 3, ks = rest >> 2;            // ks in [0,30)
        const int q = lane >> 4, c = lane & 15;
        const int pos = ks * 32 + q * 8 + j;                // [0,960)
        const int k = pos >> 6, dsw = pos & 63;
        const int d = dsw ^ ((k & 7) << 3);
        const int e = nt * 16 + c;
        union { _Float16 h; unsigned short s; } cv;
        cv.h = (_Float16)w[k * (D * D) + d * D + e];        // RNE single fp16
        wh[t] = cv.s;
    }
}

// 512 threads (8 waves), 16 points/block: halves per-point weight streaming
// (owh/owl/wh re-read once per block, blocks halved) -> ~-45% L2 read traffic.
__global__ __launch_bounds__(512, 4) void kpconv_deform(
    const float* __restrict__ qpts, const float* __restrict__ spts,
    const int*   __restrict__ nbrs, const float* __restrict__ kpts,
    const float* __restrict__ obias,
    const unsigned* __restrict__ xw,
    const unsigned short* __restrict__ owh, const unsigned short* __restrict__ owl,
    const unsigned short* __restrict__ wh,
    float* __restrict__ out)
{
    __shared__ int   s_nbr[P][M];
    __shared__ float s_q[P][3];
    __shared__ float s_off[P][E1];
    __shared__ unsigned s_act[8];
    // wfh plane: ph2->ph3 compensated-hi pair enum (1024); ph6->ph7 single, k*64+dsw
    __shared__ __align__(16) unsigned short s_wfh[P][WFS];
    // bufB multi-use (all transitions wave-private per point or barrier-fenced):
    //   ph1->ph2: aw pair planes at p*AWB (hi) / p*AWB+AWP (lo), row stride AWR=36
    //   ph2->ph3: wfl residual plane, 1024 slots at p*AWB, XOR-swz by (p&15)<<3
    //   ph3->red: s_part3 partials [8][16][49] (after in-ph3 barrier)
    //   ph5->ph6: aw hi plane (p*AWB)
    //   ph7:      s_red kk-half reduction [4][16][16] f32 (after post-ph6 barrier)
    __shared__ __align__(16) char s_bufB[P * AWB * 2];                      // 36864 B
    unsigned short* s_awB = (unsigned short*)s_bufB;
    float (*s_part3)[16][49] = (float(*)[16][49])s_bufB;                    // 25088 B
    float (*s_red)[16][16]   = (float(*)[16][16])s_bufB;                    //  4096 B

    const int tid  = threadIdx.x;
    const int base = blockIdx.x * P;
    const int lane = tid & 63;
    const int wid  = tid >> 6;                  // 0..7
    const int q    = lane >> 4, c = lane & 15;
    const int pg   = tid >> 5, mg = tid & 31;   // (p,m) mapping for ph1/ph5
    // wave w's ph1/ph5 points {2w,2w+1} == its ph2/ph6 consumers -> no barrier needed

    float nbx, nby, nbz;   // centered neighbor coords, live ph1->ph5
    f16x8 fbh[2][4];       // cached x hi fragments (ph2 -> ph6)

    if (tid < P * 3)  ((float*)s_q)[tid]  = qpts[base * 3 + tid];
    __syncthreads();

    // ---- ph1: gather, centered nb, aw1 -> compensated fp16 planes [p][k*AWR+m] ----
    {
        const int ni = nbrs[(base + pg) * M + mg];
        s_nbr[pg][mg] = ni;
        nbx = spts[ni * 3 + 0] - s_q[pg][0];
        nby = spts[ni * 3 + 1] - s_q[pg][1];
        nbz = spts[ni * 3 + 2] - s_q[pg][2];
        float av[16];
        av[15] = 0.f;                               // pad row -> exact zeros
#pragma unroll
        for (int k = 0; k < KP; k++) {              // kpts uniform -> scalar loads
            const float dx = nbx - kpts[k * 3 + 0];
            const float dy = nby - kpts[k * 3 + 1];
            const float dz = nbz - kpts[k * 3 + 2];
            av[k] = fmaxf(1.0f - sqrtf(dx * dx + dy * dy + dz * dz), 0.f);
        }
        const int awb = pg * AWB + mg;
#pragma unroll
        for (int k2 = 0; k2 < 16; k2 += 2) {
            unsigned hu, lu; split2h(av[k2], av[k2 + 1], hu, lu);
            s_awB[awb + k2 * AWR]             = (unsigned short)hu;
            s_awB[awb + (k2 + 1) * AWR]       = (unsigned short)(hu >> 16);
            s_awB[awb + AWP + k2 * AWR]       = (unsigned short)lu;
            s_awB[awb + AWP + (k2 + 1) * AWR] = (unsigned short)(lu >> 16);
        }
    }
    // no barrier: ph2 wave reads only its own writes (lgkmcnt ordering)

    // ---- ph2: wf1 via compensated f16 MFMA; cache x hi fragments ----
    // NOTE: aw[p] reads precede wfl[p] writes (same region, same wave, program
    // order preserved by may-alias LDS ops) -> safe in-place reuse.
    {
        const int hc = c >> 2;
        const uint4* __restrict__ xwq = (const uint4*)xw;
#pragma unroll
        for (int pi = 0; pi < 2; pi++) {
            const int p = 2 * wid + pi;
            const int pswz = p << 3;
            const int ab = p * AWB + (lane & 15) * AWR + q * 8;
            const f16x8 ah = *(const f16x8*)&s_awB[ab];
            const f16x8 al = *(const f16x8*)&s_awB[ab + AWP];
            uint4 g4[8];                             // row-slices: {t0..t3} per (j,c)
#pragma unroll
            for (int j = 0; j < 8; j++)
                g4[j] = xwq[s_nbr[p][q * 8 + j] * 16 + c];
#pragma unroll
            for (int t = 0; t < 4; t++) {
                union { f16x8 v; unsigned u[4]; } bh, bl;
#pragma unroll
                for (int jj = 0; jj < 4; jj++) {    // perm-unpack hi/lo planes
                    const unsigned ga = u4c(g4[2 * jj + 1], t);
                    const unsigned gb = u4c(g4[2 * jj], t);
                    bh.u[jj] = permb(ga, gb, 0x05040100u);
                    bl.u[jj] = permb(ga, gb, 0x07060302u);
                }
                fbh[pi][t] = bh.v;                   // cache hi for ph6
                f32x4 dacc = {0.f, 0.f, 0.f, 0.f};
                dacc = __builtin_amdgcn_mfma_f32_16x16x32_f16(ah, bh.v, dacc, 0, 0, 0);
                dacc = __builtin_amdgcn_mfma_f32_16x16x32_f16(ah, bl.v, dacc, 0, 0, 0);
                dacc = __builtin_amdgcn_mfma_f32_16x16x32_f16(al, bh.v, dacc, 0, 0, 0);
                unsigned h01, l01, h23, l23;
                split2h(dacc[0], dacc[1], h01, l01);
                split2h(dacc[2], dacc[3], h23, l23);
                // swizzled enum: pos = (t*16+c)*16 + 4*(q^hc) (+r)
                const int eb = (t * 16 + c) * 16 + 4 * (q ^ hc);
                *(uint2*)&s_wfh[p][eb] = make_uint2(h01, h23);
                *(uint2*)&s_awB[p * AWB + (eb ^ pswz)] = make_uint2(l01, l23);
            }
        }
    }
    __syncthreads();

    // ---- ph3: offsets via compensated f16 MFMA; 16 real A rows (points), ----
    // ---- contraction (32 ks-chunks) split over 8 waves (4 each)          ----
    {
        const int pr = lane & 15;                    // A row = point
        const int prswz = pr << 3;
        f32x4 acc0 = {0,0,0,0}, acc1 = {0,0,0,0}, acc2 = {0,0,0,0};
#pragma unroll
        for (int s = 0; s < 4; s++) {
            const int ks = wid * 4 + s;
            const int off = ks * 32 + q * 8;
            const f16x8 ahh = *(const f16x8*)&s_wfh[pr][off];
            const f16x8 all = *(const f16x8*)&s_awB[pr * AWB + (off ^ prswz)];
#pragma unroll
            for (int nt = 0; nt < 3; nt++) {
                const int f = ((ks * 3 + nt) * 64 + lane) * 8;
                const f16x8 bh = *(const f16x8*)&owh[f];
                const f16x8 bl = *(const f16x8*)&owl[f];
                f32x4* acc = (nt == 0) ? &acc0 : (nt == 1) ? &acc1 : &acc2;
                *acc = __builtin_amdgcn_mfma_f32_16x16x32_f16(ahh, bh, *acc, 0, 0, 0);
                *acc = __builtin_amdgcn_mfma_f32_16x16x32_f16(ahh, bl, *acc, 0, 0, 0);
                *acc = __builtin_amdgcn_mfma_f32_16x16x32_f16(all, bh, *acc, 0, 0, 0);
            }
        }
        __syncthreads();   // wfl (bufB) about to be clobbered by s_part3
#pragma unroll
        for (int r = 0; r < 4; r++) {
            s_part3[wid][4 * q + r][0 * 16 + c] = acc0[r];
            s_part3[wid][4 * q + r][1 * 16 + c] = acc1[r];
            s_part3[wid][4 * q + r][2 * 16 + c] = acc2[r];
        }
    }
    __syncthreads();

    // ---- reduce 8 ks-partials + bias -> offsets (fp32) ----
    for (int idx = tid; idx < P * E1; idx += 512) {
        const int p = idx / E1, e = idx % E1;
        float v = obias[e];
#pragma unroll
        for (int w8 = 0; w8 < 8; w8++)
            v += s_part3[w8][p][e];
        s_off[p][e] = v;
    }
    __syncthreads();

    // ---- ph5: aw2 (deformed) -> single fp16 plane (RNE) + joint wave mask ----
    {
        unsigned pmask = 0;
        float av[16];
        av[15] = 0.f;
#pragma unroll
        for (int k = 0; k < KP; k++) {
            const float kx = kpts[k * 3 + 0] + s_off[pg][3 * k + 0];
            const float ky = kpts[k * 3 + 1] + s_off[pg][3 * k + 1];
            const float kz = kpts[k * 3 + 2] + s_off[pg][3 * k + 2];
            const float dx = nbx - kx, dy = nby - ky, dz = nbz - kz;
            av[k] = fmaxf(1.0f - sqrtf(dx * dx + dy * dy + dz * dz), 0.f);
            pmask |= (__ballot(av[k] > 0.f) ? 1u : 0u) << k;   // union of wave's 2 pts
        }
        const int awb = pg * AWB + mg;
#pragma unroll
        for (int k2 = 0; k2 < 16; k2 += 2) {
            const unsigned hu = pkrne(av[k2], av[k2 + 1]);
            s_awB[awb + k2 * AWR]       = (unsigned short)hu;
            s_awB[awb + (k2 + 1) * AWR] = (unsigned short)(hu >> 16);
        }
        if (lane == 0) s_act[wid] = pmask;
    }
    // no barrier: ph6 wave reads only its own aw writes; s_act read after next barrier

    // ---- ph6: wf2 via single f16 MFMA, operands swapped (D[d][k]) ----
    {
#pragma unroll
        for (int pi = 0; pi < 2; pi++) {
            const int p = 2 * wid + pi;
            const f16x8 awh_f = *(const f16x8*)&s_awB[p * AWB + (lane & 15) * AWR + q * 8];
#pragma unroll
            for (int t = 0; t < 4; t++) {
                f32x4 dacc = {0.f, 0.f, 0.f, 0.f};
                dacc = __builtin_amdgcn_mfma_f32_16x16x32_f16(fbh[pi][t], awh_f, dacc, 0, 0, 0);
                // wf2[k=c][d = t*16+4q+r] single fp16 (RNE); dsw keeps 4-runs
                const unsigned u01 = pkrne(dacc[0], dacc[1]);
                const unsigned u23 = pkrne(dacc[2], dacc[3]);
                const int dsw = (t * 16 + 4 * q) ^ ((c & 7) << 3);
                *(uint2*)&s_wfh[p][c * 64 + dsw] = make_uint2(u01, u23);
            }
        }
    }
    __syncthreads();

    const unsigned u2 = s_act[0] | s_act[1] | s_act[2] | s_act[3] |
                        s_act[4] | s_act[5] | s_act[6] | s_act[7];

    // ---- ph7: output via single f16 MFMA over active k ----
    // wave = (etile, kh): 4 e-tiles x 2 kk-halves; kh pair summed via LDS.
    {
        const int etile = wid & 3, kh = wid >> 2;
        const int pr = lane & 15;                   // A row = point (16 real rows)
        f32x4 acc = {0.f, 0.f, 0.f, 0.f};
#pragma unroll
        for (int k = 0; k < KP; k++) {
            if (!((u2 >> k) & 1)) continue;
            const int ks = k * 2 + kh;              // this wave's kk half
            const f16x8 ah = *(const f16x8*)&s_wfh[pr][ks * 32 + q * 8];
            const f16x8 bh = *(const f16x8*)&wh[((ks * 4 + etile) * 64 + lane) * 8];
            acc = __builtin_amdgcn_mfma_f32_16x16x32_f16(ah, bh, acc, 0, 0, 0);
        }
        // bufB dead after ph6 barrier -> s_red[4][16][16] kk-half staging
        if (kh == 1) {
#pragma unroll
            for (int r = 0; r < 4; r++)
                s_red[etile][4 * q + r][c] = acc[r];
        }
        __syncthreads();
        if (kh == 0) {
#pragma unroll
            for (int r = 0; r < 4; r++)
                out[(base + 4 * q + r) * D + etile * 16 + c] =
                    acc[r] + s_red[etile][4 * q + r][c];
        }
    }
}

extern "C" void kernel_launch(void* const* d_in, const int* in_sizes, int n_in,
                              void* d_out, int out_size, void* d_ws, size_t ws_size,
                              hipStream_t stream) {
    const float* q   = (const float*)d_in[0];
    const float* s   = (const float*)d_in[1];
    const int*   nb  = (const int*)  d_in[2];
    const float* x   = (const float*)d_in[3];
    const float* kp  = (const float*)d_in[4];
    const float* ow  = (const float*)d_in[5];
    const float* ob  = (const float*)d_in[6];
    const float* w   = (const float*)d_in[7];
    float* out = (float*)d_out;

    unsigned*       xw  = (unsigned*)d_ws;                            // 12,800,000 B
    unsigned short* owh = (unsigned short*)((char*)d_ws + 12800000);  //     98,304 B
    unsigned short* owl = (unsigned short*)((char*)d_ws + 12898304);  //     98,304 B
    unsigned short* wh  = (unsigned short*)((char*)d_ws + 12996608);  //    122,880 B

    prep_all<<<3557, 256, 0, stream>>>(x, ow, w, xw, owh, owl, wh);
    kpconv_deform<<<N_PTS / P, 512, 0, stream>>>(q, s, nb, kp, ob,
                                                 xw, owh, owl, wh, out);
}

// Round 9
// 178.741 us; speedup vs baseline: 1.0468x; 1.0468x over previous
//
#include <hip/hip_runtime.h>

#define N_PTS 50000
#define M 32
#define KP 15
#define D 64
#define E1 45
#define P 16       // points per block (512 threads, 8 waves)
#define WFS 1048   // wfh plane row stride (ushorts): >=1024 enum slots
#define AWR 36     // aw row stride (ushorts): 18 dwords -> conflict-free b128 frags
#define AWP 576    // aw plane size (16 rows * 36)
#define AWB 1152   // per-point region stride in bufB (hi plane + lo plane)

typedef __attribute__((ext_vector_type(8))) _Float16 f16x8;
typedef __attribute__((ext_vector_type(4))) float    f32x4;
typedef __attribute__((ext_vector_type(2))) _Float16 f16x2;
typedef __attribute__((ext_vector_type(2))) __fp16   fp16v2;   // builtin return type

__device__ __forceinline__ unsigned pkrtz(float a, float b) {   // packed fp16 RTZ
    union { fp16v2 v; unsigned u; } x;
    x.v = __builtin_amdgcn_cvt_pkrtz(a, b);
    return x.u;
}
__device__ __forceinline__ unsigned pkrne(float a, float b) {   // packed fp16 RNE
    union { f16x2 v; unsigned u; } x;
    x.v[0] = (_Float16)a; x.v[1] = (_Float16)b; return x.u;
}
__device__ __forceinline__ float h2f(unsigned bits16) {
    union { unsigned short s; _Float16 h; } x; x.s = (unsigned short)bits16;
    return (float)x.h;
}
// raw v_sqrt_f32 (~1-2 ulp): avoids libm's IEEE fixup expansion (~8-10 VALU).
// 48M sqrts/dispatch made the expansion a top VALU consumer; tol absmax~0.29.
__device__ __forceinline__ float fsqrt_fast(float x) {
#if __has_builtin(__builtin_amdgcn_sqrtf)
    return __builtin_amdgcn_sqrtf(x);
#else
    return sqrtf(x);
#endif
}
// compensated fp16 split of a pair: hu = packed hi (RTZ), lu = packed residual
__device__ __forceinline__ void split2h(float a, float b, unsigned& hu, unsigned& lu) {
    hu = pkrtz(a, b);
    const float ra = a - h2f(hu & 0xffffu);
    const float rb = b - h2f(hu >> 16);
    lu = pkrtz(ra, rb);
}
// packed single value split: lo16 = fp16 hi (RNE), hi16 = fp16 residual
__device__ __forceinline__ unsigned splitpk1(float v) {
    const _Float16 h = (_Float16)v;
    const _Float16 l = (_Float16)(v - (float)h);
    union { f16x2 v2; unsigned u; } x; x.v2[0] = h; x.v2[1] = l; return x.u;
}
__device__ __forceinline__ unsigned u4c(const uint4 v, const int t) {
    return (t == 0) ? v.x : (t == 1) ? v.y : (t == 2) ? v.z : v.w;
}

#if defined(__HIP_DEVICE_COMPILE__) && __has_builtin(__builtin_amdgcn_perm)
__device__ __forceinline__ unsigned permb(unsigned a, unsigned b, unsigned sel) {
    return __builtin_amdgcn_perm(a, b, sel);
}
#else
__device__ __forceinline__ unsigned permb(unsigned a, unsigned b, unsigned sel) {
    if (sel == 0x05040100u) return (b & 0xffffu) | (a << 16);
    return (b >> 16) | (a & 0xffff0000u);
}
#endif

// ---------------- fused prep (one launch; writes d_ws) -----------------------
// blocks [0,3125): x -> packed {f16 hi, f16 residual} dwords, TRANSPOSED row
//     layout: xw[n*64 + c*4 + t] holds x[n][t*16+c]. Per thread: 4 contiguous
//     output dwords (one uint4 store), 4 stride-16 reads (line-coalesced per
//     16-lane group). R8 BUG FIX: grid must cover 800,000 uint4 stores ->
//     3125 blocks (R8's 782 left 75% of xw stale -> absmax 14.6).
// blocks [3125,3317): ow -> owh/owl fp16 planes; pos swizzle:
//     orig = pos ^ (((pos>>6)&3)<<2); d = orig>>4, k = orig&15 (zero pad k==15/e>=45)
// blocks [3317,3557): w -> wh single fp16 plane; pos = k*64+dsw, d = dsw ^ ((k&7)<<3)
__global__ void prep_all(const float* __restrict__ x, const float* __restrict__ ow,
                         const float* __restrict__ w, unsigned* __restrict__ xw,
                         unsigned short* __restrict__ owh, unsigned short* __restrict__ owl,
                         unsigned short* __restrict__ wh)
{
    const int b = blockIdx.x, tid = threadIdx.x;
    if (b < 3125) {
        const int o0 = (b * 256 + tid) * 4;          // 4 contiguous out dwords
        const int n = o0 >> 6, cc = (o0 >> 2) & 15;  // j=0..3 -> t=j, c=cc
        const float* src = x + n * 64 + cc;
        uint4 u;
        u.x = splitpk1(src[0]);
        u.y = splitpk1(src[16]);
        u.z = splitpk1(src[32]);
        u.w = splitpk1(src[48]);
        *(uint4*)&xw[o0] = u;
    } else if (b < 3317) {
        const int t = (b - 3125) * 256 + tid;               // [0, 49152)
        const int j = t & 7, lane = (t >> 3) & 63, rest = t >> 9;
        const int nt = rest % 3, ks = rest / 3;
        const int q = lane >> 4, c = lane & 15;
        const int pos  = ks * 32 + q * 8 + j;
        const int orig = pos ^ (((pos >> 6) & 3) << 2);
        const int d = orig >> 4, k = orig & 15, e = nt * 16 + c;
        const float v = (k < KP && e < E1) ? ow[k * (D * E1) + d * E1 + e] : 0.f;
        const unsigned u = splitpk1(v);
        owh[t] = (unsigned short)u;
        owl[t] = (unsigned short)(u >> 16);
    } else {
        const int t = (b - 3317) * 256 + tid;               // [0, 61440)
        const int j = t & 7, lane = (t >> 3) & 63, rest = t >> 9;
        const int nt = rest & 3, ks = rest >> 2;            // ks in [0,30)
        const int q = lane >> 4, c = lane & 15;
        const int pos = ks * 32 + q * 8 + j;                // [0,960)
        const int k = pos >> 6, dsw = pos & 63;
        const int d = dsw ^ ((k & 7) << 3);
        const int e = nt * 16 + c;
        union { _Float16 h; unsigned short s; } cv;
        cv.h = (_Float16)w[k * (D * D) + d * D + e];        // RNE single fp16
        wh[t] = cv.s;
    }
}

// 512 threads (8 waves), 16 points/block.
__global__ __launch_bounds__(512, 4) void kpconv_deform(
    const float* __restrict__ qpts, const float* __restrict__ spts,
    const int*   __restrict__ nbrs, const float* __restrict__ kpts,
    const float* __restrict__ obias,
    const unsigned* __restrict__ xw,
    const unsigned short* __restrict__ owh, const unsigned short* __restrict__ owl,
    const unsigned short* __restrict__ wh,
    float* __restrict__ out)
{
    __shared__ int   s_nbr[P][M];
    __shared__ float s_q[P][3];
    __shared__ float s_off[P][E1];
    __shared__ unsigned s_act[8];
    // wfh plane: ph2->ph3 compensated-hi pair enum (1024); ph6->ph7 single, k*64+dsw
    __shared__ __align__(16) unsigned short s_wfh[P][WFS];
    // bufB multi-use (all transitions wave-private per point or barrier-fenced):
    //   ph1->ph2: aw pair planes at p*AWB (hi) / p*AWB+AWP (lo), row stride AWR=36
    //   ph2->ph3: wfl residual plane, 1024 slots at p*AWB, XOR-swz by (p&15)<<3
    //   ph3->red: s_part3 partials [8][16][49] (after in-ph3 barrier)
    //   ph5->ph6: aw hi plane (p*AWB)
    //   ph7:      s_red kk-half reduction [4][16][16] f32 (after post-ph6 barrier)
    __shared__ __align__(16) char s_bufB[P * AWB * 2];                      // 36864 B
    unsigned short* s_awB = (unsigned short*)s_bufB;
    float (*s_part3)[16][49] = (float(*)[16][49])s_bufB;                    // 25088 B
    float (*s_red)[16][16]   = (float(*)[16][16])s_bufB;                    //  4096 B

    const int tid  = threadIdx.x;
    const int base = blockIdx.x * P;
    const int lane = tid & 63;
    const int wid  = tid >> 6;                  // 0..7
    const int q    = lane >> 4, c = lane & 15;
    const int pg   = tid >> 5, mg = tid & 31;   // (p,m) mapping for ph1/ph5
    // wave w's ph1/ph5 points {2w,2w+1} == its ph2/ph6 consumers -> no barrier needed

    float nbx, nby, nbz;   // centered neighbor coords, live ph1->ph5
    f16x8 fbh[2][4];       // cached x hi fragments (ph2 -> ph6)

    if (tid < P * 3)  ((float*)s_q)[tid]  = qpts[base * 3 + tid];
    __syncthreads();

    // ---- ph1: gather, centered nb, aw1 -> compensated fp16 planes [p][k*AWR+m] ----
    {
        const int ni = nbrs[(base + pg) * M + mg];
        s_nbr[pg][mg] = ni;
        nbx = spts[ni * 3 + 0] - s_q[pg][0];
        nby = spts[ni * 3 + 1] - s_q[pg][1];
        nbz = spts[ni * 3 + 2] - s_q[pg][2];
        float av[16];
        av[15] = 0.f;                               // pad row -> exact zeros
#pragma unroll
        for (int k = 0; k < KP; k++) {              // kpts uniform -> scalar loads
            const float dx = nbx - kpts[k * 3 + 0];
            const float dy = nby - kpts[k * 3 + 1];
            const float dz = nbz - kpts[k * 3 + 2];
            av[k] = fmaxf(1.0f - fsqrt_fast(dx * dx + dy * dy + dz * dz), 0.f);
        }
        const int awb = pg * AWB + mg;
#pragma unroll
        for (int k2 = 0; k2 < 16; k2 += 2) {
            unsigned hu, lu; split2h(av[k2], av[k2 + 1], hu, lu);
            s_awB[awb + k2 * AWR]             = (unsigned short)hu;
            s_awB[awb + (k2 + 1) * AWR]       = (unsigned short)(hu >> 16);
            s_awB[awb + AWP + k2 * AWR]       = (unsigned short)lu;
            s_awB[awb + AWP + (k2 + 1) * AWR] = (unsigned short)(lu >> 16);
        }
    }
    // no barrier: ph2 wave reads only its own writes (lgkmcnt ordering)

    // ---- ph2: wf1 via compensated f16 MFMA; cache x hi fragments ----
    // NOTE: aw[p] reads precede wfl[p] writes (same region, same wave, program
    // order preserved by may-alias LDS ops) -> safe in-place reuse.
    {
        const int hc = c >> 2;
        const uint4* __restrict__ xwq = (const uint4*)xw;
#pragma unroll
        for (int pi = 0; pi < 2; pi++) {
            const int p = 2 * wid + pi;
            const int pswz = p << 3;
            const int ab = p * AWB + (lane & 15) * AWR + q * 8;
            const f16x8 ah = *(const f16x8*)&s_awB[ab];
            const f16x8 al = *(const f16x8*)&s_awB[ab + AWP];
            uint4 g4[8];                             // row-slices: {t0..t3} per (j,c)
#pragma unroll
            for (int j = 0; j < 8; j++)
                g4[j] = xwq[s_nbr[p][q * 8 + j] * 16 + c];
#pragma unroll
            for (int t = 0; t < 4; t++) {
                union { f16x8 v; unsigned u[4]; } bh, bl;
#pragma unroll
                for (int jj = 0; jj < 4; jj++) {    // perm-unpack hi/lo planes
                    const unsigned ga = u4c(g4[2 * jj + 1], t);
                    const unsigned gb = u4c(g4[2 * jj], t);
                    bh.u[jj] = permb(ga, gb, 0x05040100u);
                    bl.u[jj] = permb(ga, gb, 0x07060302u);
                }
                fbh[pi][t] = bh.v;                   // cache hi for ph6
                f32x4 dacc = {0.f, 0.f, 0.f, 0.f};
                dacc = __builtin_amdgcn_mfma_f32_16x16x32_f16(ah, bh.v, dacc, 0, 0, 0);
                dacc = __builtin_amdgcn_mfma_f32_16x16x32_f16(ah, bl.v, dacc, 0, 0, 0);
                dacc = __builtin_amdgcn_mfma_f32_16x16x32_f16(al, bh.v, dacc, 0, 0, 0);
                unsigned h01, l01, h23, l23;
                split2h(dacc[0], dacc[1], h01, l01);
                split2h(dacc[2], dacc[3], h23, l23);
                // swizzled enum: pos = (t*16+c)*16 + 4*(q^hc) (+r)
                const int eb = (t * 16 + c) * 16 + 4 * (q ^ hc);
                *(uint2*)&s_wfh[p][eb] = make_uint2(h01, h23);
                *(uint2*)&s_awB[p * AWB + (eb ^ pswz)] = make_uint2(l01, l23);
            }
        }
    }
    __syncthreads();

    // ---- ph3: offsets via compensated f16 MFMA; 16 real A rows (points), ----
    // ---- contraction (32 ks-chunks) split over 8 waves (4 each)          ----
    {
        const int pr = lane & 15;                    // A row = point
        const int prswz = pr << 3;
        f32x4 acc0 = {0,0,0,0}, acc1 = {0,0,0,0}, acc2 = {0,0,0,0};
#pragma unroll
        for (int s = 0; s < 4; s++) {
            const int ks = wid * 4 + s;
            const int off = ks * 32 + q * 8;
            const f16x8 ahh = *(const f16x8*)&s_wfh[pr][off];
            const f16x8 all = *(const f16x8*)&s_awB[pr * AWB + (off ^ prswz)];
#pragma unroll
            for (int nt = 0; nt < 3; nt++) {
                const int f = ((ks * 3 + nt) * 64 + lane) * 8;
                const f16x8 bh = *(const f16x8*)&owh[f];
                const f16x8 bl = *(const f16x8*)&owl[f];
                f32x4* acc = (nt == 0) ? &acc0 : (nt == 1) ? &acc1 : &acc2;
                *acc = __builtin_amdgcn_mfma_f32_16x16x32_f16(ahh, bh, *acc, 0, 0, 0);
                *acc = __builtin_amdgcn_mfma_f32_16x16x32_f16(ahh, bl, *acc, 0, 0, 0);
                *acc = __builtin_amdgcn_mfma_f32_16x16x32_f16(all, bh, *acc, 0, 0, 0);
            }
        }
        __syncthreads();   // wfl (bufB) about to be clobbered by s_part3
#pragma unroll
        for (int r = 0; r < 4; r++) {
            s_part3[wid][4 * q + r][0 * 16 + c] = acc0[r];
            s_part3[wid][4 * q + r][1 * 16 + c] = acc1[r];
            s_part3[wid][4 * q + r][2 * 16 + c] = acc2[r];
        }
    }
    __syncthreads();

    // ---- reduce 8 ks-partials + bias -> offsets (fp32) ----
    for (int idx = tid; idx < P * E1; idx += 512) {
        const int p = idx / E1, e = idx % E1;
        float v = obias[e];
#pragma unroll
        for (int w8 = 0; w8 < 8; w8++)
            v += s_part3[w8][p][e];
        s_off[p][e] = v;
    }
    __syncthreads();

    // ---- ph5: aw2 (deformed) -> single fp16 plane (RNE) + joint wave mask ----
    {
        unsigned pmask = 0;
        float av[16];
        av[15] = 0.f;
#pragma unroll
        for (int k = 0; k < KP; k++) {
            const float kx = kpts[k * 3 + 0] + s_off[pg][3 * k + 0];
            const float ky = kpts[k * 3 + 1] + s_off[pg][3 * k + 1];
            const float kz = kpts[k * 3 + 2] + s_off[pg][3 * k + 2];
            const float dx = nbx - kx, dy = nby - ky, dz = nbz - kz;
            av[k] = fmaxf(1.0f - fsqrt_fast(dx * dx + dy * dy + dz * dz), 0.f);
            pmask |= (__ballot(av[k] > 0.f) ? 1u : 0u) << k;   // union of wave's 2 pts
        }
        const int awb = pg * AWB + mg;
#pragma unroll
        for (int k2 = 0; k2 < 16; k2 += 2) {
            const unsigned hu = pkrne(av[k2], av[k2 + 1]);
            s_awB[awb + k2 * AWR]       = (unsigned short)hu;
            s_awB[awb + (k2 + 1) * AWR] = (unsigned short)(hu >> 16);
        }
        if (lane == 0) s_act[wid] = pmask;
    }
    // no barrier: ph6 wave reads only its own aw writes; s_act read after next barrier

    // ---- ph6: wf2 via single f16 MFMA, operands swapped (D[d][k]) ----
    {
#pragma unroll
        for (int pi = 0; pi < 2; pi++) {
            const int p = 2 * wid + pi;
            const f16x8 awh_f = *(const f16x8*)&s_awB[p * AWB + (lane & 15) * AWR + q * 8];
#pragma unroll
            for (int t = 0; t < 4; t++) {
                f32x4 dacc = {0.f, 0.f, 0.f, 0.f};
                dacc = __builtin_amdgcn_mfma_f32_16x16x32_f16(fbh[pi][t], awh_f, dacc, 0, 0, 0);
                // wf2[k=c][d = t*16+4q+r] single fp16 (RNE); dsw keeps 4-runs
                const unsigned u01 = pkrne(dacc[0], dacc[1]);
                const unsigned u23 = pkrne(dacc[2], dacc[3]);
                const int dsw = (t * 16 + 4 * q) ^ ((c & 7) << 3);
                *(uint2*)&s_wfh[p][c * 64 + dsw] = make_uint2(u01, u23);
            }
        }
    }
    __syncthreads();

    const unsigned u2 = s_act[0] | s_act[1] | s_act[2] | s_act[3] |
                        s_act[4] | s_act[5] | s_act[6] | s_act[7];

    // ---- ph7: output via single f16 MFMA over active k ----
    // wave = (etile, kh): 4 e-tiles x 2 kk-halves; kh pair summed via LDS.
    {
        const int etile = wid & 3, kh = wid >> 2;
        const int pr = lane & 15;                   // A row = point (16 real rows)
        f32x4 acc = {0.f, 0.f, 0.f, 0.f};
#pragma unroll
        for (int k = 0; k < KP; k++) {
            if (!((u2 >> k) & 1)) continue;
            const int ks = k * 2 + kh;              // this wave's kk half
            const f16x8 ah = *(const f16x8*)&s_wfh[pr][ks * 32 + q * 8];
            const f16x8 bh = *(const f16x8*)&wh[((ks * 4 + etile) * 64 + lane) * 8];
            acc = __builtin_amdgcn_mfma_f32_16x16x32_f16(ah, bh, acc, 0, 0, 0);
        }
        // bufB dead after ph6 barrier -> s_red[4][16][16] kk-half staging
        if (kh == 1) {
#pragma unroll
            for (int r = 0; r < 4; r++)
                s_red[etile][4 * q + r][c] = acc[r];
        }
        __syncthreads();
        if (kh == 0) {
#pragma unroll
            for (int r = 0; r < 4; r++)
                out[(base + 4 * q + r) * D + etile * 16 + c] =
                    acc[r] + s_red[etile][4 * q + r][c];
        }
    }
}

extern "C" void kernel_launch(void* const* d_in, const int* in_sizes, int n_in,
                              void* d_out, int out_size, void* d_ws, size_t ws_size,
                              hipStream_t stream) {
    const float* q   = (const float*)d_in[0];
    const float* s   = (const float*)d_in[1];
    const int*   nb  = (const int*)  d_in[2];
    const float* x   = (const float*)d_in[3];
    const float* kp  = (const float*)d_in[4];
    const float* ow  = (const float*)d_in[5];
    const float* ob  = (const float*)d_in[6];
    const float* w   = (const float*)d_in[7];
    float* out = (float*)d_out;

    unsigned*       xw  = (unsigned*)d_ws;                            // 12,800,000 B
    unsigned short* owh = (unsigned short*)((char*)d_ws + 12800000);  //     98,304 B
    unsigned short* owl = (unsigned short*)((char*)d_ws + 12898304);  //     98,304 B
    unsigned short* wh  = (unsigned short*)((char*)d_ws + 12996608);  //    122,880 B

    prep_all<<<3557, 256, 0, stream>>>(x, ow, w, xw, owh, owl, wh);
    kpconv_deform<<<N_PTS / P, 512, 0, stream>>>(q, s, nb, kp, ob,
                                                 xw, owh, owl, wh, out);
}

// Round 10
// 160.005 us; speedup vs baseline: 1.1694x; 1.1171x over previous
//
#include <hip/hip_runtime.h>

#define N_PTS 50000
#define M 32
#define KP 15
#define D 64
#define E1 45
#define P 16       // points per block (512 threads, 8 waves)
#define WFS 1048   // wfh plane row stride (ushorts): >=1024 enum slots
#define AWR 36     // aw row stride (ushorts): 18 dwords -> conflict-free b128 frags
#define AWP 576    // aw plane size (16 rows * 36)
#define AWB 1152   // per-point region stride in bufB (hi plane + lo plane)

typedef __attribute__((ext_vector_type(8))) _Float16 f16x8;
typedef __attribute__((ext_vector_type(4))) float    f32x4;
typedef __attribute__((ext_vector_type(2))) _Float16 f16x2;
typedef __attribute__((ext_vector_type(2))) __fp16   fp16v2;   // builtin return type

__device__ __forceinline__ unsigned pkrtz(float a, float b) {   // packed fp16 RTZ
    union { fp16v2 v; unsigned u; } x;
    x.v = __builtin_amdgcn_cvt_pkrtz(a, b);
    return x.u;
}
__device__ __forceinline__ unsigned pkrne(float a, float b) {   // packed fp16 RNE
    union { f16x2 v; unsigned u; } x;
    x.v[0] = (_Float16)a; x.v[1] = (_Float16)b; return x.u;
}
__device__ __forceinline__ float h2f(unsigned bits16) {
    union { unsigned short s; _Float16 h; } x; x.s = (unsigned short)bits16;
    return (float)x.h;
}
// raw v_sqrt_f32 (~1-2 ulp): avoids libm's IEEE fixup expansion (~8-10 VALU).
// R9-verified: VALUBusy 54->38%, -8us. tol absmax~0.29.
__device__ __forceinline__ float fsqrt_fast(float x) {
#if __has_builtin(__builtin_amdgcn_sqrtf)
    return __builtin_amdgcn_sqrtf(x);
#else
    return sqrtf(x);
#endif
}
// compensated fp16 split of a pair: hu = packed hi (RTZ), lu = packed residual
__device__ __forceinline__ void split2h(float a, float b, unsigned& hu, unsigned& lu) {
    hu = pkrtz(a, b);
    const float ra = a - h2f(hu & 0xffffu);
    const float rb = b - h2f(hu >> 16);
    lu = pkrtz(ra, rb);
}

#if defined(__HIP_DEVICE_COMPILE__) && __has_builtin(__builtin_amdgcn_perm)
__device__ __forceinline__ unsigned permb(unsigned a, unsigned b, unsigned sel) {
    return __builtin_amdgcn_perm(a, b, sel);
}
#else
__device__ __forceinline__ unsigned permb(unsigned a, unsigned b, unsigned sel) {
    if (sel == 0x05040100u) return (b & 0xffffu) | (a << 16);
    return (b >> 16) | (a & 0xffff0000u);
}
#endif

// ---------------- fused prep (one launch; writes d_ws) -----------------------
// blocks [0,3125): x -> fp16-only rows (R10: residual plane DROPPED to halve
//     the gather payload; 12.8MB -> 6.4MB table, 256B -> 128B per row read).
//     layout (uint2 view): xw2[n*16 + c] = { pkrne(x[n][c],    x[n][16+c]),
//                                            pkrne(x[n][32+c], x[n][48+c]) }
//     i.e. component .x = {t0,t1}, .y = {t2,t3} for feature t*16+c.
// blocks [3125,3317): ow -> owh/owl fp16 planes; pos swizzle:
//     orig = pos ^ (((pos>>6)&3)<<2); d = orig>>4, k = orig&15 (zero pad k==15/e>=45)
// blocks [3317,3557): w -> wh single fp16 plane; pos = k*64+dsw, d = dsw ^ ((k&7)<<3)
__global__ void prep_all(const float* __restrict__ x, const float* __restrict__ ow,
                         const float* __restrict__ w, unsigned* __restrict__ xw,
                         unsigned short* __restrict__ owh, unsigned short* __restrict__ owl,
                         unsigned short* __restrict__ wh)
{
    const int b = blockIdx.x, tid = threadIdx.x;
    if (b < 3125) {
        const int i = b * 256 + tid;                 // [0, 800000) = one (n,c)
        const int n = i >> 4, c = i & 15;
        const float* src = x + n * 64 + c;           // 4 stride-16 reads, coalesced
        uint2 u;
        u.x = pkrne(src[0],  src[16]);               // {t0, t1}
        u.y = pkrne(src[32], src[48]);               // {t2, t3}
        ((uint2*)xw)[i] = u;                         // i == n*16+c, contiguous 8B
    } else if (b < 3317) {
        const int t = (b - 3125) * 256 + tid;               // [0, 49152)
        const int j = t & 7, lane = (t >> 3) & 63, rest = t >> 9;
        const int nt = rest % 3, ks = rest / 3;
        const int q = lane >> 4, c = lane & 15;
        const int pos  = ks * 32 + q * 8 + j;
        const int orig = pos ^ (((pos >> 6) & 3) << 2);
        const int d = orig >> 4, k = orig & 15, e = nt * 16 + c;
        const float v = (k < KP && e < E1) ? ow[k * (D * E1) + d * E1 + e] : 0.f;
        unsigned hu, lu; split2h(v, 0.f, hu, lu);
        owh[t] = (unsigned short)hu;
        owl[t] = (unsigned short)lu;
    } else {
        const int t = (b - 3317) * 256 + tid;               // [0, 61440)
        const int j = t & 7, lane = (t >> 3) & 63, rest = t >> 9;
        const int nt = rest & 3, ks = rest >> 2;            // ks in [0,30)
        const int q = lane >> 4, c = lane & 15;
        const int pos = ks * 32 + q * 8 + j;                // [0,960)
        const int k = pos >> 6, dsw = pos & 63;
        const int d = dsw ^ ((k & 7) << 3);
        const int e = nt * 16 + c;
        union { _Float16 h; unsigned short s; } cv;
        cv.h = (_Float16)w[k * (D * D) + d * D + e];        // RNE single fp16
        wh[t] = cv.s;
    }
}

// 512 threads (8 waves), 16 points/block.
__global__ __launch_bounds__(512, 4) void kpconv_deform(
    const float* __restrict__ qpts, const float* __restrict__ spts,
    const int*   __restrict__ nbrs, const float* __restrict__ kpts,
    const float* __restrict__ obias,
    const unsigned* __restrict__ xw,
    const unsigned short* __restrict__ owh, const unsigned short* __restrict__ owl,
    const unsigned short* __restrict__ wh,
    float* __restrict__ out)
{
    __shared__ int   s_nbr[P][M];
    __shared__ float s_q[P][3];
    __shared__ float s_off[P][E1];
    __shared__ unsigned s_act[8];
    // wfh plane: ph2->ph3 compensated-hi pair enum (1024); ph6->ph7 single, k*64+dsw
    __shared__ __align__(16) unsigned short s_wfh[P][WFS];
    // bufB multi-use (all transitions wave-private per point or barrier-fenced):
    //   ph1->ph2: aw pair planes at p*AWB (hi) / p*AWB+AWP (lo), row stride AWR=36
    //   ph2->ph3: wfl residual plane, 1024 slots at p*AWB, XOR-swz by (p&15)<<3
    //   ph3->red: s_part3 partials [8][16][49] (after in-ph3 barrier)
    //   ph5->ph6: aw hi plane (p*AWB)
    //   ph7:      s_red kk-half reduction [4][16][16] f32 (after post-ph6 barrier)
    __shared__ __align__(16) char s_bufB[P * AWB * 2];                      // 36864 B
    unsigned short* s_awB = (unsigned short*)s_bufB;
    float (*s_part3)[16][49] = (float(*)[16][49])s_bufB;                    // 25088 B
    float (*s_red)[16][16]   = (float(*)[16][16])s_bufB;                    //  4096 B

    const int tid  = threadIdx.x;
    const int base = blockIdx.x * P;
    const int lane = tid & 63;
    const int wid  = tid >> 6;                  // 0..7
    const int q    = lane >> 4, c = lane & 15;
    const int pg   = tid >> 5, mg = tid & 31;   // (p,m) mapping for ph1/ph5
    // wave w's ph1/ph5 points {2w,2w+1} == its ph2/ph6 consumers -> no barrier needed

    float nbx, nby, nbz;   // centered neighbor coords, live ph1->ph5
    f16x8 fbh[2][4];       // cached x fp16 fragments (ph2 -> ph6)

    if (tid < P * 3)  ((float*)s_q)[tid]  = qpts[base * 3 + tid];
    __syncthreads();

    // ---- ph1: gather, centered nb, aw1 -> compensated fp16 planes [p][k*AWR+m] ----
    {
        const int ni = nbrs[(base + pg) * M + mg];
        s_nbr[pg][mg] = ni;
        nbx = spts[ni * 3 + 0] - s_q[pg][0];
        nby = spts[ni * 3 + 1] - s_q[pg][1];
        nbz = spts[ni * 3 + 2] - s_q[pg][2];
        float av[16];
        av[15] = 0.f;                               // pad row -> exact zeros
#pragma unroll
        for (int k = 0; k < KP; k++) {              // kpts uniform -> scalar loads
            const float dx = nbx - kpts[k * 3 + 0];
            const float dy = nby - kpts[k * 3 + 1];
            const float dz = nbz - kpts[k * 3 + 2];
            av[k] = fmaxf(1.0f - fsqrt_fast(dx * dx + dy * dy + dz * dz), 0.f);
        }
        const int awb = pg * AWB + mg;
#pragma unroll
        for (int k2 = 0; k2 < 16; k2 += 2) {
            unsigned hu, lu; split2h(av[k2], av[k2 + 1], hu, lu);
            s_awB[awb + k2 * AWR]             = (unsigned short)hu;
            s_awB[awb + (k2 + 1) * AWR]       = (unsigned short)(hu >> 16);
            s_awB[awb + AWP + k2 * AWR]       = (unsigned short)lu;
            s_awB[awb + AWP + (k2 + 1) * AWR] = (unsigned short)(lu >> 16);
        }
    }
    // no barrier: ph2 wave reads only its own writes (lgkmcnt ordering)

    // ---- ph2: wf1 via compensated-aw f16 MFMA; x is fp16-only (R10) ----
    // wf1 = (ah + al) * bh : 2 MFMAs per t (the ah*bl residual term is dropped
    // with the xw residual plane; ph6 already consumed hi-only -> identical).
    {
        const int hc = c >> 2;
        const uint2* __restrict__ xwq = (const uint2*)xw;
#pragma unroll
        for (int pi = 0; pi < 2; pi++) {
            const int p = 2 * wid + pi;
            const int pswz = p << 3;
            const int ab = p * AWB + (lane & 15) * AWR + q * 8;
            const f16x8 ah = *(const f16x8*)&s_awB[ab];
            const f16x8 al = *(const f16x8*)&s_awB[ab + AWP];
            uint2 g2[8];                             // row-slices: {t01, t23} per (j,c)
#pragma unroll
            for (int j = 0; j < 8; j++)
                g2[j] = xwq[s_nbr[p][q * 8 + j] * 16 + c];
#pragma unroll
            for (int t = 0; t < 4; t++) {
                union { f16x8 v; unsigned u[4]; } bh;
#pragma unroll
                for (int jj = 0; jj < 4; jj++) {    // pick t's half of each pair
                    const unsigned ga = (t < 2) ? g2[2 * jj + 1].x : g2[2 * jj + 1].y;
                    const unsigned gb = (t < 2) ? g2[2 * jj].x     : g2[2 * jj].y;
                    bh.u[jj] = permb(ga, gb, (t & 1) ? 0x07060302u : 0x05040100u);
                }
                fbh[pi][t] = bh.v;                   // cache for ph6
                f32x4 dacc = {0.f, 0.f, 0.f, 0.f};
                dacc = __builtin_amdgcn_mfma_f32_16x16x32_f16(ah, bh.v, dacc, 0, 0, 0);
                dacc = __builtin_amdgcn_mfma_f32_16x16x32_f16(al, bh.v, dacc, 0, 0, 0);
                unsigned h01, l01, h23, l23;
                split2h(dacc[0], dacc[1], h01, l01);
                split2h(dacc[2], dacc[3], h23, l23);
                // swizzled enum: pos = (t*16+c)*16 + 4*(q^hc) (+r)
                const int eb = (t * 16 + c) * 16 + 4 * (q ^ hc);
                *(uint2*)&s_wfh[p][eb] = make_uint2(h01, h23);
                *(uint2*)&s_awB[p * AWB + (eb ^ pswz)] = make_uint2(l01, l23);
            }
        }
    }
    __syncthreads();

    // ---- ph3: offsets via compensated f16 MFMA; 16 real A rows (points), ----
    // ---- contraction (32 ks-chunks) split over 8 waves (4 each)          ----
    {
        const int pr = lane & 15;                    // A row = point
        const int prswz = pr << 3;
        f32x4 acc0 = {0,0,0,0}, acc1 = {0,0,0,0}, acc2 = {0,0,0,0};
#pragma unroll
        for (int s = 0; s < 4; s++) {
            const int ks = wid * 4 + s;
            const int off = ks * 32 + q * 8;
            const f16x8 ahh = *(const f16x8*)&s_wfh[pr][off];
            const f16x8 all = *(const f16x8*)&s_awB[pr * AWB + (off ^ prswz)];
#pragma unroll
            for (int nt = 0; nt < 3; nt++) {
                const int f = ((ks * 3 + nt) * 64 + lane) * 8;
                const f16x8 bh = *(const f16x8*)&owh[f];
                const f16x8 bl = *(const f16x8*)&owl[f];
                f32x4* acc = (nt == 0) ? &acc0 : (nt == 1) ? &acc1 : &acc2;
                *acc = __builtin_amdgcn_mfma_f32_16x16x32_f16(ahh, bh, *acc, 0, 0, 0);
                *acc = __builtin_amdgcn_mfma_f32_16x16x32_f16(ahh, bl, *acc, 0, 0, 0);
                *acc = __builtin_amdgcn_mfma_f32_16x16x32_f16(all, bh, *acc, 0, 0, 0);
            }
        }
        __syncthreads();   // wfl (bufB) about to be clobbered by s_part3
#pragma unroll
        for (int r = 0; r < 4; r++) {
            s_part3[wid][4 * q + r][0 * 16 + c] = acc0[r];
            s_part3[wid][4 * q + r][1 * 16 + c] = acc1[r];
            s_part3[wid][4 * q + r][2 * 16 + c] = acc2[r];
        }
    }
    __syncthreads();

    // ---- reduce 8 ks-partials + bias -> offsets (fp32) ----
    for (int idx = tid; idx < P * E1; idx += 512) {
        const int p = idx / E1, e = idx % E1;
        float v = obias[e];
#pragma unroll
        for (int w8 = 0; w8 < 8; w8++)
            v += s_part3[w8][p][e];
        s_off[p][e] = v;
    }
    __syncthreads();

    // ---- ph5: aw2 (deformed) -> single fp16 plane (RNE) + joint wave mask ----
    {
        unsigned pmask = 0;
        float av[16];
        av[15] = 0.f;
#pragma unroll
        for (int k = 0; k < KP; k++) {
            const float kx = kpts[k * 3 + 0] + s_off[pg][3 * k + 0];
            const float ky = kpts[k * 3 + 1] + s_off[pg][3 * k + 1];
            const float kz = kpts[k * 3 + 2] + s_off[pg][3 * k + 2];
            const float dx = nbx - kx, dy = nby - ky, dz = nbz - kz;
            av[k] = fmaxf(1.0f - fsqrt_fast(dx * dx + dy * dy + dz * dz), 0.f);
            pmask |= (__ballot(av[k] > 0.f) ? 1u : 0u) << k;   // union of wave's 2 pts
        }
        const int awb = pg * AWB + mg;
#pragma unroll
        for (int k2 = 0; k2 < 16; k2 += 2) {
            const unsigned hu = pkrne(av[k2], av[k2 + 1]);
            s_awB[awb + k2 * AWR]       = (unsigned short)hu;
            s_awB[awb + (k2 + 1) * AWR] = (unsigned short)(hu >> 16);
        }
        if (lane == 0) s_act[wid] = pmask;
    }
    // no barrier: ph6 wave reads only its own aw writes; s_act read after next barrier

    // ---- ph6: wf2 via single f16 MFMA, operands swapped (D[d][k]) ----
    {
#pragma unroll
        for (int pi = 0; pi < 2; pi++) {
            const int p = 2 * wid + pi;
            const f16x8 awh_f = *(const f16x8*)&s_awB[p * AWB + (lane & 15) * AWR + q * 8];
#pragma unroll
            for (int t = 0; t < 4; t++) {
                f32x4 dacc = {0.f, 0.f, 0.f, 0.f};
                dacc = __builtin_amdgcn_mfma_f32_16x16x32_f16(fbh[pi][t], awh_f, dacc, 0, 0, 0);
                // wf2[k=c][d = t*16+4q+r] single fp16 (RNE); dsw keeps 4-runs
                const unsigned u01 = pkrne(dacc[0], dacc[1]);
                const unsigned u23 = pkrne(dacc[2], dacc[3]);
                const int dsw = (t * 16 + 4 * q) ^ ((c & 7) << 3);
                *(uint2*)&s_wfh[p][c * 64 + dsw] = make_uint2(u01, u23);
            }
        }
    }
    __syncthreads();

    const unsigned u2 = s_act[0] | s_act[1] | s_act[2] | s_act[3] |
                        s_act[4] | s_act[5] | s_act[6] | s_act[7];

    // ---- ph7: output via single f16 MFMA over active k ----
    // wave = (etile, kh): 4 e-tiles x 2 kk-halves; kh pair summed via LDS.
    {
        const int etile = wid & 3, kh = wid >> 2;
        const int pr = lane & 15;                   // A row = point (16 real rows)
        f32x4 acc = {0.f, 0.f, 0.f, 0.f};
#pragma unroll
        for (int k = 0; k < KP; k++) {
            if (!((u2 >> k) & 1)) continue;
            const int ks = k * 2 + kh;              // this wave's kk half
            const f16x8 ah = *(const f16x8*)&s_wfh[pr][ks * 32 + q * 8];
            const f16x8 bh = *(const f16x8*)&wh[((ks * 4 + etile) * 64 + lane) * 8];
            acc = __builtin_amdgcn_mfma_f32_16x16x32_f16(ah, bh, acc, 0, 0, 0);
        }
        // bufB dead after ph6 barrier -> s_red[4][16][16] kk-half staging
        if (kh == 1) {
#pragma unroll
            for (int r = 0; r < 4; r++)
                s_red[etile][4 * q + r][c] = acc[r];
        }
        __syncthreads();
        if (kh == 0) {
#pragma unroll
            for (int r = 0; r < 4; r++)
                out[(base + 4 * q + r) * D + etile * 16 + c] =
                    acc[r] + s_red[etile][4 * q + r][c];
        }
    }
}

extern "C" void kernel_launch(void* const* d_in, const int* in_sizes, int n_in,
                              void* d_out, int out_size, void* d_ws, size_t ws_size,
                              hipStream_t stream) {
    const float* q   = (const float*)d_in[0];
    const float* s   = (const float*)d_in[1];
    const int*   nb  = (const int*)  d_in[2];
    const float* x   = (const float*)d_in[3];
    const float* kp  = (const float*)d_in[4];
    const float* ow  = (const float*)d_in[5];
    const float* ob  = (const float*)d_in[6];
    const float* w   = (const float*)d_in[7];
    float* out = (float*)d_out;

    // xw now fp16-only: 6,400,000 B used of its region (offsets kept stable)
    unsigned*       xw  = (unsigned*)d_ws;
    unsigned short* owh = (unsigned short*)((char*)d_ws + 12800000);  //     98,304 B
    unsigned short* owl = (unsigned short*)((char*)d_ws + 12898304);  //     98,304 B
    unsigned short* wh  = (unsigned short*)((char*)d_ws + 12996608);  //    122,880 B

    prep_all<<<3557, 256, 0, stream>>>(x, ow, w, xw, owh, owl, wh);
    kpconv_deform<<<N_PTS / P, 512, 0, stream>>>(q, s, nb, kp, ob,
                                                 xw, owh, owl, wh, out);
}

// Round 11
// 157.045 us; speedup vs baseline: 1.1914x; 1.0188x over previous
//
#include <hip/hip_runtime.h>

#define N_PTS 50000
#define M 32
#define KP 15
#define D 64
#define E1 45
#define P 16       // points per block (512 threads, 8 waves)
#define WFS 1048   // wfh plane row stride (ushorts): >=1024 enum slots
#define AWR 36     // aw row stride (ushorts): 18 dwords -> conflict-free b128 frags
#define AWB 576    // per-point aw plane stride (single fp16 plane, 16 rows * 36)

typedef __attribute__((ext_vector_type(8))) _Float16 f16x8;
typedef __attribute__((ext_vector_type(4))) float    f32x4;
typedef __attribute__((ext_vector_type(2))) _Float16 f16x2;
typedef __attribute__((ext_vector_type(2))) __fp16   fp16v2;   // builtin return type

__device__ __forceinline__ unsigned pkrtz(float a, float b) {   // packed fp16 RTZ
    union { fp16v2 v; unsigned u; } x;
    x.v = __builtin_amdgcn_cvt_pkrtz(a, b);
    return x.u;
}
__device__ __forceinline__ unsigned pkrne(float a, float b) {   // packed fp16 RNE
    union { f16x2 v; unsigned u; } x;
    x.v[0] = (_Float16)a; x.v[1] = (_Float16)b; return x.u;
}
__device__ __forceinline__ float h2f(unsigned bits16) {
    union { unsigned short s; _Float16 h; } x; x.s = (unsigned short)bits16;
    return (float)x.h;
}
// raw v_sqrt_f32 (~1-2 ulp): avoids libm's IEEE fixup expansion (~8-10 VALU).
// R9-verified: VALUBusy 54->38%, -8us. tol absmax~0.29.
__device__ __forceinline__ float fsqrt_fast(float x) {
#if __has_builtin(__builtin_amdgcn_sqrtf)
    return __builtin_amdgcn_sqrtf(x);
#else
    return sqrtf(x);
#endif
}
// compensated fp16 split of a pair: hu = packed hi (RTZ), lu = packed residual
// (retained for the ow weight planes only — R11 dropped aw1/wf1 compensation;
//  absmax sat at the 0.0625 output-quantization floor through every internal
//  precision change, so those planes bought nothing.)
__device__ __forceinline__ void split2h(float a, float b, unsigned& hu, unsigned& lu) {
    hu = pkrtz(a, b);
    const float ra = a - h2f(hu & 0xffffu);
    const float rb = b - h2f(hu >> 16);
    lu = pkrtz(ra, rb);
}

#if defined(__HIP_DEVICE_COMPILE__) && __has_builtin(__builtin_amdgcn_perm)
__device__ __forceinline__ unsigned permb(unsigned a, unsigned b, unsigned sel) {
    return __builtin_amdgcn_perm(a, b, sel);
}
#else
__device__ __forceinline__ unsigned permb(unsigned a, unsigned b, unsigned sel) {
    if (sel == 0x05040100u) return (b & 0xffffu) | (a << 16);
    return (b >> 16) | (a & 0xffff0000u);
}
#endif

// ---------------- fused prep (one launch; writes d_ws) -----------------------
// blocks [0,3125): x -> fp16-only rows (R10): 6.4MB table, 128B per row.
//     layout (uint2 view): xw2[n*16 + c] = { pkrne(x[n][c],    x[n][16+c]),
//                                            pkrne(x[n][32+c], x[n][48+c]) }
// blocks [3125,3317): ow -> owh/owl fp16 planes (compensated); pos swizzle:
//     orig = pos ^ (((pos>>6)&3)<<2); d = orig>>4, k = orig&15 (zero pad k==15/e>=45)
// blocks [3317,3557): w -> wh single fp16 plane; pos = k*64+dsw, d = dsw ^ ((k&7)<<3)
__global__ void prep_all(const float* __restrict__ x, const float* __restrict__ ow,
                         const float* __restrict__ w, unsigned* __restrict__ xw,
                         unsigned short* __restrict__ owh, unsigned short* __restrict__ owl,
                         unsigned short* __restrict__ wh)
{
    const int b = blockIdx.x, tid = threadIdx.x;
    if (b < 3125) {
        const int i = b * 256 + tid;                 // [0, 800000) = one (n,c)
        const int n = i >> 4, c = i & 15;
        const float* src = x + n * 64 + c;           // 4 stride-16 reads, coalesced
        uint2 u;
        u.x = pkrne(src[0],  src[16]);               // {t0, t1}
        u.y = pkrne(src[32], src[48]);               // {t2, t3}
        ((uint2*)xw)[i] = u;                         // i == n*16+c, contiguous 8B
    } else if (b < 3317) {
        const int t = (b - 3125) * 256 + tid;               // [0, 49152)
        const int j = t & 7, lane = (t >> 3) & 63, rest = t >> 9;
        const int nt = rest % 3, ks = rest / 3;
        const int q = lane >> 4, c = lane & 15;
        const int pos  = ks * 32 + q * 8 + j;
        const int orig = pos ^ (((pos >> 6) & 3) << 2);
        const int d = orig >> 4, k = orig & 15, e = nt * 16 + c;
        const float v = (k < KP && e < E1) ? ow[k * (D * E1) + d * E1 + e] : 0.f;
        unsigned hu, lu; split2h(v, 0.f, hu, lu);
        owh[t] = (unsigned short)hu;
        owl[t] = (unsigned short)lu;
    } else {
        const int t = (b - 3317) * 256 + tid;               // [0, 61440)
        const int j = t & 7, lane = (t >> 3) & 63, rest = t >> 9;
        const int nt = rest & 3, ks = rest >> 2;            // ks in [0,30)
        const int q = lane >> 4, c = lane & 15;
        const int pos = ks * 32 + q * 8 + j;                // [0,960)
        const int k = pos >> 6, dsw = pos & 63;
        const int d = dsw ^ ((k & 7) << 3);
        const int e = nt * 16 + c;
        union { _Float16 h; unsigned short s; } cv;
        cv.h = (_Float16)w[k * (D * D) + d * D + e];        // RNE single fp16
        wh[t] = cv.s;
    }
}

// 512 threads (8 waves), 16 points/block.
__global__ __launch_bounds__(512, 4) void kpconv_deform(
    const float* __restrict__ qpts, const float* __restrict__ spts,
    const int*   __restrict__ nbrs, const float* __restrict__ kpts,
    const float* __restrict__ obias,
    const unsigned* __restrict__ xw,
    const unsigned short* __restrict__ owh, const unsigned short* __restrict__ owl,
    const unsigned short* __restrict__ wh,
    float* __restrict__ out)
{
    __shared__ int   s_nbr[P][M];
    __shared__ float s_q[P][3];
    __shared__ float s_off[P][E1];
    __shared__ unsigned s_act[8];
    // wfh plane: ph2->ph3 single-fp16 enum (1024 slots); ph6->ph7 single, k*64+dsw
    __shared__ __align__(16) unsigned short s_wfh[P][WFS];
    // bufB multi-use (transitions barrier-fenced or wave-private):
    //   ph1->ph2: aw1 single fp16 plane at p*AWB, row stride AWR (dead after ph2)
    //   ph3->red: s_part3 partials [8][16][49] (written after post-ph2 barrier,
    //             aw1 dead by then -> NO mid-ph3 barrier needed anymore)
    //   ph5->ph6: aw2 single plane (p*AWB; part3 dead after reduce barrier)
    //   ph7:      s_red kk-half staging [4][16][16] f32 (after post-ph6 barrier)
    __shared__ __align__(16) char s_bufB[25088];
    unsigned short* s_awB = (unsigned short*)s_bufB;
    float (*s_part3)[16][49] = (float(*)[16][49])s_bufB;                    // 25088 B
    float (*s_red)[16][16]   = (float(*)[16][16])s_bufB;                    //  4096 B

    const int tid  = threadIdx.x;
    const int base = blockIdx.x * P;
    const int lane = tid & 63;
    const int wid  = tid >> 6;                  // 0..7
    const int q    = lane >> 4, c = lane & 15;
    const int pg   = tid >> 5, mg = tid & 31;   // (p,m) mapping for ph1/ph5
    // wave w's ph1/ph5 points {2w,2w+1} == its ph2/ph6 consumers -> no barrier needed

    float nbx, nby, nbz;   // centered neighbor coords, live ph1->ph5
    f16x8 fbh[2][4];       // cached x fp16 fragments (ph2 -> ph6)

    if (tid < P * 3)  ((float*)s_q)[tid]  = qpts[base * 3 + tid];
    __syncthreads();

    // ---- ph1: gather, centered nb, aw1 -> single fp16 plane [p][k*AWR+m] ----
    {
        const int ni = nbrs[(base + pg) * M + mg];
        s_nbr[pg][mg] = ni;
        nbx = spts[ni * 3 + 0] - s_q[pg][0];
        nby = spts[ni * 3 + 1] - s_q[pg][1];
        nbz = spts[ni * 3 + 2] - s_q[pg][2];
        float av[16];
        av[15] = 0.f;                               // pad row -> exact zeros
#pragma unroll
        for (int k = 0; k < KP; k++) {              // kpts uniform -> scalar loads
            const float dx = nbx - kpts[k * 3 + 0];
            const float dy = nby - kpts[k * 3 + 1];
            const float dz = nbz - kpts[k * 3 + 2];
            av[k] = fmaxf(1.0f - fsqrt_fast(dx * dx + dy * dy + dz * dz), 0.f);
        }
        const int awb = pg * AWB + mg;
#pragma unroll
        for (int k2 = 0; k2 < 16; k2 += 2) {
            const unsigned hu = pkrne(av[k2], av[k2 + 1]);
            s_awB[awb + k2 * AWR]       = (unsigned short)hu;
            s_awB[awb + (k2 + 1) * AWR] = (unsigned short)(hu >> 16);
        }
    }
    // no barrier: ph2 wave reads only its own writes (lgkmcnt ordering)

    // ---- ph2: wf1 via single f16 MFMA (aw1 fp16, x fp16); cache x fragments ----
    {
        const int hc = c >> 2;
        const uint2* __restrict__ xwq = (const uint2*)xw;
#pragma unroll
        for (int pi = 0; pi < 2; pi++) {
            const int p = 2 * wid + pi;
            const int ab = p * AWB + (lane & 15) * AWR + q * 8;
            const f16x8 ah = *(const f16x8*)&s_awB[ab];
            uint2 g2[8];                             // row-slices: {t01, t23} per (j,c)
#pragma unroll
            for (int j = 0; j < 8; j++)
                g2[j] = xwq[s_nbr[p][q * 8 + j] * 16 + c];
#pragma unroll
            for (int t = 0; t < 4; t++) {
                union { f16x8 v; unsigned u[4]; } bh;
#pragma unroll
                for (int jj = 0; jj < 4; jj++) {    // pick t's half of each pair
                    const unsigned ga = (t < 2) ? g2[2 * jj + 1].x : g2[2 * jj + 1].y;
                    const unsigned gb = (t < 2) ? g2[2 * jj].x     : g2[2 * jj].y;
                    bh.u[jj] = permb(ga, gb, (t & 1) ? 0x07060302u : 0x05040100u);
                }
                fbh[pi][t] = bh.v;                   // cache for ph6
                f32x4 dacc = {0.f, 0.f, 0.f, 0.f};
                dacc = __builtin_amdgcn_mfma_f32_16x16x32_f16(ah, bh.v, dacc, 0, 0, 0);
                // wf1 -> single fp16 (RNE), swizzled enum:
                // pos = (t*16+c)*16 + 4*(q^hc) (+r)
                const unsigned u01 = pkrne(dacc[0], dacc[1]);
                const unsigned u23 = pkrne(dacc[2], dacc[3]);
                const int eb = (t * 16 + c) * 16 + 4 * (q ^ hc);
                *(uint2*)&s_wfh[p][eb] = make_uint2(u01, u23);
            }
        }
    }
    __syncthreads();

    // ---- ph3: offsets via f16 MFMA (A = wf1 fp16, B = compensated ow);   ----
    // ---- 16 real A rows (points), contraction split over 8 waves (4 ks) ----
    // aw1 plane (bufB) died at the barrier above -> part3 writes are safe
    // without an intra-ph3 barrier.
    {
        const int pr = lane & 15;                    // A row = point
        f32x4 acc0 = {0,0,0,0}, acc1 = {0,0,0,0}, acc2 = {0,0,0,0};
#pragma unroll
        for (int s = 0; s < 4; s++) {
            const int ks = wid * 4 + s;
            const f16x8 ahh = *(const f16x8*)&s_wfh[pr][ks * 32 + q * 8];
#pragma unroll
            for (int nt = 0; nt < 3; nt++) {
                const int f = ((ks * 3 + nt) * 64 + lane) * 8;
                const f16x8 bh = *(const f16x8*)&owh[f];
                const f16x8 bl = *(const f16x8*)&owl[f];
                f32x4* acc = (nt == 0) ? &acc0 : (nt == 1) ? &acc1 : &acc2;
                *acc = __builtin_amdgcn_mfma_f32_16x16x32_f16(ahh, bh, *acc, 0, 0, 0);
                *acc = __builtin_amdgcn_mfma_f32_16x16x32_f16(ahh, bl, *acc, 0, 0, 0);
            }
        }
#pragma unroll
        for (int r = 0; r < 4; r++) {
            s_part3[wid][4 * q + r][0 * 16 + c] = acc0[r];
            s_part3[wid][4 * q + r][1 * 16 + c] = acc1[r];
            s_part3[wid][4 * q + r][2 * 16 + c] = acc2[r];
        }
    }
    __syncthreads();

    // ---- reduce 8 ks-partials + bias -> offsets (fp32) ----
    for (int idx = tid; idx < P * E1; idx += 512) {
        const int p = idx / E1, e = idx % E1;
        float v = obias[e];
#pragma unroll
        for (int w8 = 0; w8 < 8; w8++)
            v += s_part3[w8][p][e];
        s_off[p][e] = v;
    }
    __syncthreads();

    // ---- ph5: aw2 (deformed) -> single fp16 plane (RNE) + joint wave mask ----
    {
        unsigned pmask = 0;
        float av[16];
        av[15] = 0.f;
#pragma unroll
        for (int k = 0; k < KP; k++) {
            const float kx = kpts[k * 3 + 0] + s_off[pg][3 * k + 0];
            const float ky = kpts[k * 3 + 1] + s_off[pg][3 * k + 1];
            const float kz = kpts[k * 3 + 2] + s_off[pg][3 * k + 2];
            const float dx = nbx - kx, dy = nby - ky, dz = nbz - kz;
            av[k] = fmaxf(1.0f - fsqrt_fast(dx * dx + dy * dy + dz * dz), 0.f);
            pmask |= (__ballot(av[k] > 0.f) ? 1u : 0u) << k;   // union of wave's 2 pts
        }
        const int awb = pg * AWB + mg;
#pragma unroll
        for (int k2 = 0; k2 < 16; k2 += 2) {
            const unsigned hu = pkrne(av[k2], av[k2 + 1]);
            s_awB[awb + k2 * AWR]       = (unsigned short)hu;
            s_awB[awb + (k2 + 1) * AWR] = (unsigned short)(hu >> 16);
        }
        if (lane == 0) s_act[wid] = pmask;
    }
    // no barrier: ph6 wave reads only its own aw writes; s_act read after next barrier

    // ---- ph6: wf2 via single f16 MFMA, operands swapped (D[d][k]) ----
    {
#pragma unroll
        for (int pi = 0; pi < 2; pi++) {
            const int p = 2 * wid + pi;
            const f16x8 awh_f = *(const f16x8*)&s_awB[p * AWB + (lane & 15) * AWR + q * 8];
#pragma unroll
            for (int t = 0; t < 4; t++) {
                f32x4 dacc = {0.f, 0.f, 0.f, 0.f};
                dacc = __builtin_amdgcn_mfma_f32_16x16x32_f16(fbh[pi][t], awh_f, dacc, 0, 0, 0);
                // wf2[k=c][d = t*16+4q+r] single fp16 (RNE); dsw keeps 4-runs
                const unsigned u01 = pkrne(dacc[0], dacc[1]);
                const unsigned u23 = pkrne(dacc[2], dacc[3]);
                const int dsw = (t * 16 + 4 * q) ^ ((c & 7) << 3);
                *(uint2*)&s_wfh[p][c * 64 + dsw] = make_uint2(u01, u23);
            }
        }
    }
    __syncthreads();

    const unsigned u2 = s_act[0] | s_act[1] | s_act[2] | s_act[3] |
                        s_act[4] | s_act[5] | s_act[6] | s_act[7];

    // ---- ph7: output via single f16 MFMA over active k ----
    // wave = (etile, kh): 4 e-tiles x 2 kk-halves; kh pair summed via LDS.
    {
        const int etile = wid & 3, kh = wid >> 2;
        const int pr = lane & 15;                   // A row = point (16 real rows)
        f32x4 acc = {0.f, 0.f, 0.f, 0.f};
#pragma unroll
        for (int k = 0; k < KP; k++) {
            if (!((u2 >> k) & 1)) continue;
            const int ks = k * 2 + kh;              // this wave's kk half
            const f16x8 ah = *(const f16x8*)&s_wfh[pr][ks * 32 + q * 8];
            const f16x8 bh = *(const f16x8*)&wh[((ks * 4 + etile) * 64 + lane) * 8];
            acc = __builtin_amdgcn_mfma_f32_16x16x32_f16(ah, bh, acc, 0, 0, 0);
        }
        // bufB dead after ph6 barrier -> s_red[4][16][16] kk-half staging
        if (kh == 1) {
#pragma unroll
            for (int r = 0; r < 4; r++)
                s_red[etile][4 * q + r][c] = acc[r];
        }
        __syncthreads();
        if (kh == 0) {
#pragma unroll
            for (int r = 0; r < 4; r++)
                out[(base + 4 * q + r) * D + etile * 16 + c] =
                    acc[r] + s_red[etile][4 * q + r][c];
        }
    }
}

extern "C" void kernel_launch(void* const* d_in, const int* in_sizes, int n_in,
                              void* d_out, int out_size, void* d_ws, size_t ws_size,
                              hipStream_t stream) {
    const float* q   = (const float*)d_in[0];
    const float* s   = (const float*)d_in[1];
    const int*   nb  = (const int*)  d_in[2];
    const float* x   = (const float*)d_in[3];
    const float* kp  = (const float*)d_in[4];
    const float* ow  = (const float*)d_in[5];
    const float* ob  = (const float*)d_in[6];
    const float* w   = (const float*)d_in[7];
    float* out = (float*)d_out;

    // xw fp16-only: 6,400,000 B used of its region (offsets kept stable)
    unsigned*       xw  = (unsigned*)d_ws;
    unsigned short* owh = (unsigned short*)((char*)d_ws + 12800000);  //     98,304 B
    unsigned short* owl = (unsigned short*)((char*)d_ws + 12898304);  //     98,304 B
    unsigned short* wh  = (unsigned short*)((char*)d_ws + 12996608);  //    122,880 B

    prep_all<<<3557, 256, 0, stream>>>(x, ow, w, xw, owh, owl, wh);
    kpconv_deform<<<N_PTS / P, 512, 0, stream>>>(q, s, nb, kp, ob,
                                                 xw, owh, owl, wh, out);
}

// Round 14
// 151.640 us; speedup vs baseline: 1.2339x; 1.0356x over previous
//
#include <hip/hip_runtime.h>

#define N_PTS 50000
#define M 32
#define KP 15
#define D 64
#define E1 45
#define P 16       // points per block (512 threads, 8 waves)
#define WFS 1032   // wfh plane stride (ushorts): 1024 slots + 8 pad
                   // row stride 516 dw -> start banks 4*pr%32: 8 starts, 2-way (free)

typedef __attribute__((ext_vector_type(8))) _Float16 f16x8;
typedef __attribute__((ext_vector_type(4))) float    f32x4;
typedef __attribute__((ext_vector_type(2))) _Float16 f16x2;
typedef __attribute__((ext_vector_type(2))) __fp16   fp16v2;   // builtin return type

__device__ __forceinline__ unsigned pkrtz(float a, float b) {   // packed fp16 RTZ
    union { fp16v2 v; unsigned u; } x;
    x.v = __builtin_amdgcn_cvt_pkrtz(a, b);
    return x.u;
}
__device__ __forceinline__ unsigned pkrne(float a, float b) {   // packed fp16 RNE
    union { f16x2 v; unsigned u; } x;
    x.v[0] = (_Float16)a; x.v[1] = (_Float16)b; return x.u;
}
__device__ __forceinline__ float h2f(unsigned bits16) {
    union { unsigned short s; _Float16 h; } x; x.s = (unsigned short)bits16;
    return (float)x.h;
}
// raw v_sqrt_f32 (~1-2 ulp): avoids libm's IEEE fixup expansion (~8-10 VALU).
// R9-verified: VALUBusy 54->38%, -8us. tol absmax~0.29.
__device__ __forceinline__ float fsqrt_fast(float x) {
#if __has_builtin(__builtin_amdgcn_sqrtf)
    return __builtin_amdgcn_sqrtf(x);
#else
    return sqrtf(x);
#endif
}
// compensated fp16 split (ow weight planes only)
__device__ __forceinline__ void split2h(float a, float b, unsigned& hu, unsigned& lu) {
    hu = pkrtz(a, b);
    const float ra = a - h2f(hu & 0xffffu);
    const float rb = b - h2f(hu >> 16);
    lu = pkrtz(ra, rb);
}
// aw plane layout: [16 rows][32 cols] ushort, 16B-granule XOR swizzle (g ^= row&3)
// -> conflict-free b128 row reads with NO padding (512 ushort/point), 16B-aligned.
__device__ __forceinline__ int aw_w(int k, int m) {        // elem (row k, col m)
    return k * 32 + ((((m >> 3) ^ k) & 3) << 3) + (m & 7);
}
__device__ __forceinline__ int aw_r8(int row, int g) {     // 8-elem granule g of row
    return row * 32 + (((g ^ row) & 3) << 3);
}

#if defined(__HIP_DEVICE_COMPILE__) && __has_builtin(__builtin_amdgcn_perm)
__device__ __forceinline__ unsigned permb(unsigned a, unsigned b, unsigned sel) {
    return __builtin_amdgcn_perm(a, b, sel);
}
#else
__device__ __forceinline__ unsigned permb(unsigned a, unsigned b, unsigned sel) {
    if (sel == 0x05040100u) return (b & 0xffffu) | (a << 16);
    return (b >> 16) | (a & 0xffff0000u);
}
#endif

// ---------------- fused prep (one launch; writes d_ws) -----------------------
// blocks [0,3125): x -> fp16-only rows: 6.4MB table, 128B per row.
//     layout (uint2 view): xw2[n*16 + c] = { pkrne(x[n][c],    x[n][16+c]),
//                                            pkrne(x[n][32+c], x[n][48+c]) }
// blocks [3125,3317): ow -> owh/owl fp16 planes (compensated); pos swizzle:
//     orig = pos ^ (((pos>>6)&3)<<2); d = orig>>4, k = orig&15 (zero pad k==15/e>=45)
// blocks [3317,3557): w -> wh single fp16 plane; pos = k*64+dsw, d = dsw ^ ((k&7)<<3)
__global__ void prep_all(const float* __restrict__ x, const float* __restrict__ ow,
                         const float* __restrict__ w, unsigned* __restrict__ xw,
                         unsigned short* __restrict__ owh, unsigned short* __restrict__ owl,
                         unsigned short* __restrict__ wh)
{
    const int b = blockIdx.x, tid = threadIdx.x;
    if (b < 3125) {
        const int i = b * 256 + tid;                 // [0, 800000) = one (n,c)
        const int n = i >> 4, c = i & 15;
        const float* src = x + n * 64 + c;           // 4 stride-16 reads, coalesced
        uint2 u;
        u.x = pkrne(src[0],  src[16]);               // {t0, t1}
        u.y = pkrne(src[32], src[48]);               // {t2, t3}
        ((uint2*)xw)[i] = u;                         // i == n*16+c, contiguous 8B
    } else if (b < 3317) {
        const int t = (b - 3125) * 256 + tid;               // [0, 49152)
        const int j = t & 7, lane = (t >> 3) & 63, rest = t >> 9;
        const int nt = rest % 3, ks = rest / 3;
        const int q = lane >> 4, c = lane & 15;
        const int pos  = ks * 32 + q * 8 + j;
        const int orig = pos ^ (((pos >> 6) & 3) << 2);
        const int d = orig >> 4, k = orig & 15, e = nt * 16 + c;
        const float v = (k < KP && e < E1) ? ow[k * (D * E1) + d * E1 + e] : 0.f;
        unsigned hu, lu; split2h(v, 0.f, hu, lu);
        owh[t] = (unsigned short)hu;
        owl[t] = (unsigned short)lu;
    } else {
        const int t = (b - 3317) * 256 + tid;               // [0, 61440)
        const int j = t & 7, lane = (t >> 3) & 63, rest = t >> 9;
        const int nt = rest & 3, ks = rest >> 2;            // ks in [0,30)
        const int q = lane >> 4, c = lane & 15;
        const int pos = ks * 32 + q * 8 + j;                // [0,960)
        const int k = pos >> 6, dsw = pos & 63;
        const int d = dsw ^ ((k & 7) << 3);
        const int e = nt * 16 + c;
        union { _Float16 h; unsigned short s; } cv;
        cv.h = (_Float16)w[k * (D * D) + d * D + e];        // RNE single fp16
        wh[t] = cv.s;
    }
}

// 512 threads (8 waves), 16 points/block, LDS 53,504 B -> 3 blocks/CU (24 waves).
__global__ __launch_bounds__(512, 6) void kpconv_deform(
    const float* __restrict__ qpts, const float* __restrict__ spts,
    const int*   __restrict__ nbrs, const float* __restrict__ kpts,
    const float* __restrict__ obias,
    const unsigned* __restrict__ xw,
    const unsigned short* __restrict__ owh, const unsigned short* __restrict__ owl,
    const unsigned short* __restrict__ wh,
    float* __restrict__ out)
{
    __shared__ __align__(16) unsigned short s_nbr[P][M];    // ushort idx (<65536)
    __shared__ float s_q[P][3];
    __shared__ float s_off[P][E1];
    // wfh planes (16 x 1032 ushort = 33,024 B), triple-duty:
    //   ph2->ph3: wf1 fp16 enum (1024 slots/point)
    //   ph3->red: s_part3 [8][16][49] f32 = 25,088 B ALIASED (after in-ph3 barrier;
    //             store index nt*16+c reaches 47 -> inner dim 49 = 48 + 1 pad)
    //   ph6->ph7: wf2 single plane, k*64+dsw
    //   s_act:    plane-w pad hole at [w][1024] (4B each; enum slots never reach it;
    //             written in ph5 AFTER part3 is dead, read after ph6 barrier)
    __shared__ __align__(16) unsigned short s_wfh[P][WFS];
    // aw planes (16 x 512 ushort = 16,384 B, XOR-swizzled granules), dual-duty:
    //   ph1->ph2: aw1 plane / ph5->ph6: aw2 plane (wave-private per point)
    //   ph7:      s_red [4][16][16] f32 = 4,096 B ALIASED (after post-ph6 barrier)
    __shared__ __align__(16) unsigned short s_awB[P * 512];
    float (*s_part3)[16][49] = (float(*)[16][49])s_wfh;
    float (*s_red)[16][16]   = (float(*)[16][16])s_awB;

    const int tid  = threadIdx.x;
    const int base = blockIdx.x * P;
    const int lane = tid & 63;
    const int wid  = tid >> 6;                  // 0..7
    const int q    = lane >> 4, c = lane & 15;
    const int pg   = tid >> 5, mg = tid & 31;   // (p,m) mapping for ph1/ph5
    // wave w's ph1/ph5 points {2w,2w+1} == its ph2/ph6 consumers -> no barrier needed

    float nbx, nby, nbz;   // centered neighbor coords, live ph1->ph5
    f16x8 fbh[2][4];       // cached x fp16 fragments (ph2 -> ph6)

    if (tid < P * 3)  ((float*)s_q)[tid]  = qpts[base * 3 + tid];
    __syncthreads();

    // ---- ph1: gather, centered nb, aw1 -> swizzled fp16 plane ----
    {
        const int ni = nbrs[(base + pg) * M + mg];
        s_nbr[pg][mg] = (unsigned short)ni;
        nbx = spts[ni * 3 + 0] - s_q[pg][0];
        nby = spts[ni * 3 + 1] - s_q[pg][1];
        nbz = spts[ni * 3 + 2] - s_q[pg][2];
        float av[16];
        av[15] = 0.f;                               // pad row -> exact zeros
#pragma unroll
        for (int k = 0; k < KP; k++) {              // kpts uniform -> scalar loads
            const float dx = nbx - kpts[k * 3 + 0];
            const float dy = nby - kpts[k * 3 + 1];
            const float dz = nbz - kpts[k * 3 + 2];
            av[k] = fmaxf(1.0f - fsqrt_fast(dx * dx + dy * dy + dz * dz), 0.f);
        }
        const int awp = pg * 512;
#pragma unroll
        for (int k2 = 0; k2 < 16; k2 += 2) {
            const unsigned hu = pkrne(av[k2], av[k2 + 1]);
            s_awB[awp + aw_w(k2, mg)]     = (unsigned short)hu;
            s_awB[awp + aw_w(k2 + 1, mg)] = (unsigned short)(hu >> 16);
        }
    }
    // no barrier: ph2 wave reads only its own writes (lgkmcnt ordering)

    // ---- ph2: wf1 via single f16 MFMA (aw1 fp16, x fp16); cache x fragments ----
    {
        const int hc = c >> 2;
        const uint2* __restrict__ xwq = (const uint2*)xw;
#pragma unroll
        for (int pi = 0; pi < 2; pi++) {
            const int p = 2 * wid + pi;
            const f16x8 ah = *(const f16x8*)&s_awB[p * 512 + aw_r8(lane & 15, q)];
            uint2 g2[8];                             // row-slices: {t01, t23} per (j,c)
#pragma unroll
            for (int j = 0; j < 8; j++)
                g2[j] = xwq[(int)s_nbr[p][q * 8 + j] * 16 + c];
#pragma unroll
            for (int t = 0; t < 4; t++) {
                union { f16x8 v; unsigned u[4]; } bh;
#pragma unroll
                for (int jj = 0; jj < 4; jj++) {    // pick t's half of each pair
                    const unsigned ga = (t < 2) ? g2[2 * jj + 1].x : g2[2 * jj + 1].y;
                    const unsigned gb = (t < 2) ? g2[2 * jj].x     : g2[2 * jj].y;
                    bh.u[jj] = permb(ga, gb, (t & 1) ? 0x07060302u : 0x05040100u);
                }
                fbh[pi][t] = bh.v;                   // cache for ph6
                f32x4 dacc = {0.f, 0.f, 0.f, 0.f};
                dacc = __builtin_amdgcn_mfma_f32_16x16x32_f16(ah, bh.v, dacc, 0, 0, 0);
                // wf1 -> single fp16 (RNE), swizzled enum:
                // pos = (t*16+c)*16 + 4*(q^hc) (+r)
                const unsigned u01 = pkrne(dacc[0], dacc[1]);
                const unsigned u23 = pkrne(dacc[2], dacc[3]);
                const int eb = (t * 16 + c) * 16 + 4 * (q ^ hc);
                *(uint2*)&s_wfh[p][eb] = make_uint2(u01, u23);
            }
        }
    }
    __syncthreads();

    // ---- ph3: offsets via f16 MFMA (A = wf1 fp16, B = compensated ow);   ----
    // ---- 16 real A rows (points), contraction split over 8 waves (4 ks) ----
    {
        const int pr = lane & 15;                    // A row = point
        f32x4 acc0 = {0,0,0,0}, acc1 = {0,0,0,0}, acc2 = {0,0,0,0};
#pragma unroll
        for (int s = 0; s < 4; s++) {
            const int ks = wid * 4 + s;
            const f16x8 ahh = *(const f16x8*)&s_wfh[pr][ks * 32 + q * 8];
#pragma unroll
            for (int nt = 0; nt < 3; nt++) {
                const int f = ((ks * 3 + nt) * 64 + lane) * 8;
                const f16x8 bh = *(const f16x8*)&owh[f];
                const f16x8 bl = *(const f16x8*)&owl[f];
                f32x4* acc = (nt == 0) ? &acc0 : (nt == 1) ? &acc1 : &acc2;
                *acc = __builtin_amdgcn_mfma_f32_16x16x32_f16(ahh, bh, *acc, 0, 0, 0);
                *acc = __builtin_amdgcn_mfma_f32_16x16x32_f16(ahh, bl, *acc, 0, 0, 0);
            }
        }
        __syncthreads();   // part3 ALIASES wfh: all waves' wf1 reads must finish
#pragma unroll
        for (int r = 0; r < 4; r++) {
            s_part3[wid][4 * q + r][0 * 16 + c] = acc0[r];
            s_part3[wid][4 * q + r][1 * 16 + c] = acc1[r];
            s_part3[wid][4 * q + r][2 * 16 + c] = acc2[r];
        }
    }
    __syncthreads();

    // ---- reduce 8 ks-partials + bias -> offsets (fp32) ----
    for (int idx = tid; idx < P * E1; idx += 512) {
        const int p = idx / E1, e = idx % E1;
        float v = obias[e];
#pragma unroll
        for (int w8 = 0; w8 < 8; w8++)
            v += s_part3[w8][p][e];
        s_off[p][e] = v;
    }
    __syncthreads();

    // ---- ph5: aw2 (deformed) -> swizzled fp16 plane + joint wave mask ----
    {
        unsigned pmask = 0;
        float av[16];
        av[15] = 0.f;
#pragma unroll
        for (int k = 0; k < KP; k++) {
            const float kx = kpts[k * 3 + 0] + s_off[pg][3 * k + 0];
            const float ky = kpts[k * 3 + 1] + s_off[pg][3 * k + 1];
            const float kz = kpts[k * 3 + 2] + s_off[pg][3 * k + 2];
            const float dx = nbx - kx, dy = nby - ky, dz = nbz - kz;
            av[k] = fmaxf(1.0f - fsqrt_fast(dx * dx + dy * dy + dz * dz), 0.f);
            pmask |= (__ballot(av[k] > 0.f) ? 1u : 0u) << k;   // union of wave's 2 pts
        }
        const int awp = pg * 512;
#pragma unroll
        for (int k2 = 0; k2 < 16; k2 += 2) {
            const unsigned hu = pkrne(av[k2], av[k2 + 1]);
            s_awB[awp + aw_w(k2, mg)]     = (unsigned short)hu;
            s_awB[awp + aw_w(k2 + 1, mg)] = (unsigned short)(hu >> 16);
        }
        if (lane == 0) *(unsigned*)&s_wfh[wid][1024] = pmask;  // pad-hole s_act
    }
    // no barrier: ph6 wave reads only its own aw writes; holes read after barrier

    // ---- ph6: wf2 via single f16 MFMA, operands swapped (D[d][k]) ----
    {
#pragma unroll
        for (int pi = 0; pi < 2; pi++) {
            const int p = 2 * wid + pi;
            const f16x8 awh_f = *(const f16x8*)&s_awB[p * 512 + aw_r8(lane & 15, q)];
#pragma unroll
            for (int t = 0; t < 4; t++) {
                f32x4 dacc = {0.f, 0.f, 0.f, 0.f};
                dacc = __builtin_amdgcn_mfma_f32_16x16x32_f16(fbh[pi][t], awh_f, dacc, 0, 0, 0);
                // wf2[k=c][d = t*16+4q+r] single fp16 (RNE); dsw keeps 4-runs
                const unsigned u01 = pkrne(dacc[0], dacc[1]);
                const unsigned u23 = pkrne(dacc[2], dacc[3]);
                const int dsw = (t * 16 + 4 * q) ^ ((c & 7) << 3);
                *(uint2*)&s_wfh[p][c * 64 + dsw] = make_uint2(u01, u23);
            }
        }
    }
    __syncthreads();

    unsigned u2 = 0;
#pragma unroll
    for (int w = 0; w < 8; w++) u2 |= *(const unsigned*)&s_wfh[w][1024];

    // ---- ph7: output via single f16 MFMA over active k ----
    // wave = (etile, kh): 4 e-tiles x 2 kk-halves; kh pair summed via LDS.
    {
        const int etile = wid & 3, kh = wid >> 2;
        const int pr = lane & 15;                   // A row = point (16 real rows)
        f32x4 acc = {0.f, 0.f, 0.f, 0.f};
#pragma unroll
        for (int k = 0; k < KP; k++) {
            if (!((u2 >> k) & 1)) continue;
            const int ks = k * 2 + kh;              // this wave's kk half
            const f16x8 ah = *(const f16x8*)&s_wfh[pr][ks * 32 + q * 8];
            const f16x8 bh = *(const f16x8*)&wh[((ks * 4 + etile) * 64 + lane) * 8];
            acc = __builtin_amdgcn_mfma_f32_16x16x32_f16(ah, bh, acc, 0, 0, 0);
        }
        // aw planes dead after ph6 barrier -> s_red[4][16][16] kk-half staging
        if (kh == 1) {
#pragma unroll
            for (int r = 0; r < 4; r++)
                s_red[etile][4 * q + r][c] = acc[r];
        }
        __syncthreads();
        if (kh == 0) {
#pragma unroll
            for (int r = 0; r < 4; r++)
                out[(base + 4 * q + r) * D + etile * 16 + c] =
                    acc[r] + s_red[etile][4 * q + r][c];
        }
    }
}

extern "C" void kernel_launch(void* const* d_in, const int* in_sizes, int n_in,
                              void* d_out, int out_size, void* d_ws, size_t ws_size,
                              hipStream_t stream) {
    const float* q   = (const float*)d_in[0];
    const float* s   = (const float*)d_in[1];
    const int*   nb  = (const int*)  d_in[2];
    const float* x   = (const float*)d_in[3];
    const float* kp  = (const float*)d_in[4];
    const float* ow  = (const float*)d_in[5];
    const float* ob  = (const float*)d_in[6];
    const float* w   = (const float*)d_in[7];
    float* out = (float*)d_out;

    // xw fp16-only: 6,400,000 B used of its region (offsets kept stable)
    unsigned*       xw  = (unsigned*)d_ws;
    unsigned short* owh = (unsigned short*)((char*)d_ws + 12800000);  //     98,304 B
    unsigned short* owl = (unsigned short*)((char*)d_ws + 12898304);  //     98,304 B
    unsigned short* wh  = (unsigned short*)((char*)d_ws + 12996608);  //    122,880 B

    prep_all<<<3557, 256, 0, stream>>>(x, ow, w, xw, owh, owl, wh);
    kpconv_deform<<<N_PTS / P, 512, 0, stream>>>(q, s, nb, kp, ob,
                                                 xw, owh, owl, wh, out);
}